// Round 3
// baseline (370.747 us; speedup 1.0000x reference)
//
#include <hip/hip_runtime.h>
#include <stdint.h>

typedef short bf16x8 __attribute__((ext_vector_type(8)));
typedef float f32x4 __attribute__((ext_vector_type(4)));

__device__ __forceinline__ float gelu_exact(float v) {
  return 0.5f * v * (1.0f + erff(v * 0.70710678118654752f));
}

__device__ __forceinline__ short f2bf(float x) {  // RNE f32->bf16
  uint32_t u = __float_as_uint(x);
  u += 0x7fffu + ((u >> 16) & 1u);
  return (short)(u >> 16);
}

// ---------------------------------------------------------------------------
// Dtype detector: even-index 16-bit halves of x. bf16 data -> proper N(0,1)
// bf16 values (biased exp in [112,134] ~always). fp32 data -> those halves are
// low mantissa bits, uniform -> ~9% hit. flag=1 means bf16 inputs.
// ---------------------------------------------------------------------------
__global__ void detect_kernel(const unsigned short* __restrict__ x16, int* __restrict__ flag) {
  const int l = threadIdx.x;  // 64 lanes
  int cnt = 0;
#pragma unroll
  for (int i = 0; i < 16; ++i) {
    unsigned short v = x16[(l * 16 + i) * 2];
    int ex = (v >> 7) & 0xFF;
    if (ex >= 112 && ex <= 134) cnt++;
  }
  for (int o = 32; o > 0; o >>= 1) cnt += __shfl_down(cnt, o);
  if (l == 0) *flag = (cnt >= 512) ? 1 : 0;
}

// ---------------------------------------------------------------------------
// X -> bf16 contiguous copy/cast into ws.
// ---------------------------------------------------------------------------
__global__ __launch_bounds__(256)
void prep_x(const void* __restrict__ xin, short* __restrict__ Xb,
            const int* __restrict__ flag) {
  const int idx = (blockIdx.x * 256 + threadIdx.x) * 8;
  if (*flag) {
    *(bf16x8*)(Xb + idx) = *(const bf16x8*)((const short*)xin + idx);
  } else {
    const float* xf = (const float*)xin;
    bf16x8 o;
#pragma unroll
    for (int u = 0; u < 8; ++u) o[u] = f2bf(xf[idx + u]);
    *(bf16x8*)(Xb + idx) = o;
  }
}

// ---------------------------------------------------------------------------
// Per-expert transpose (+cast): dst[e][c][r] = src[e][r][c], bf16 out.
// ---------------------------------------------------------------------------
__global__ __launch_bounds__(256)
void prep_w(const void* __restrict__ src, short* __restrict__ dst,
            const int* __restrict__ flag, int R, int C) {
  __shared__ __align__(16) short T[64][72];
  const int ez = blockIdx.z;
  const int r0 = blockIdx.x * 64, c0 = blockIdx.y * 64;
  const int t = threadIdx.x, i = t >> 3, j8 = t & 7;
  const bool isbf = (*flag != 0);
#pragma unroll
  for (int p = 0; p < 2; ++p) {
    int ii = i + p * 32;
    if (isbf) {
      const short* s = (const short*)src + (size_t)ez * R * C;
      *(bf16x8*)(&T[ii][j8 * 8]) = *(const bf16x8*)(s + (size_t)(r0 + ii) * C + c0 + j8 * 8);
    } else {
      const float* s = (const float*)src + (size_t)ez * R * C;
#pragma unroll
      for (int u = 0; u < 8; ++u)
        T[ii][j8 * 8 + u] = f2bf(s[(size_t)(r0 + ii) * C + c0 + j8 * 8 + u]);
    }
  }
  __syncthreads();
#pragma unroll
  for (int p = 0; p < 2; ++p) {
    int ii = i + p * 32;
    bf16x8 v;
#pragma unroll
    for (int u = 0; u < 8; ++u) v[u] = T[j8 * 8 + u][ii];
    *(bf16x8*)(dst + (size_t)ez * R * C + (size_t)(c0 + ii) * R + r0 + j8 * 8) = v;
  }
}

// ---------------------------------------------------------------------------
// Fused experts. One block = 128-token tile x 1 expert, 4 waves (2x2 of 64x64).
// Conservative single-buffered staging (VGPR -> ds_write_b128).
// Xb: [8192][512] bf16. W1T: [16][512 h][512 d]. W2T: [16][128 d4][512 h].
// OUT: fp32 [8192 row][128 d4][16 e].
// ---------------------------------------------------------------------------
__global__ __launch_bounds__(256, 2)
void moe_kernel(const short* __restrict__ Xb, const short* __restrict__ W1T,
                const short* __restrict__ W2T, float* __restrict__ OUT)
{
  __shared__ __align__(16) short Xs[128 * 72];   // [128 m][64 k] pad->72
  __shared__ __align__(16) short Ws[128 * 72];   // [128 n][64 k] pad->72
  __shared__ __align__(16) short HL[128 * 136];  // [128 m][128 h] pad->136

  const int tid = threadIdx.x;
  const int l = tid & 63, w = tid >> 6;
  const int wm = w & 1, wn = w >> 1;
  const int e = blockIdx.x & 15;        // 16 experts of a tile co-resident (L2 merge of strided out)
  const int tile = blockIdx.x >> 4;

  const int sr = tid >> 3;              // staging: row 0..31 (+p*32)
  const int sc = (tid & 7) * 8;         // staging col in shorts

  const size_t xbase  = (size_t)(tile * 128) * 512;
  const size_t w1base = (size_t)e * (512 * 512);
  const size_t w2base = (size_t)e * (128 * 512);

  const int lm = l & 15, lq = l >> 4;
  const int aoff = (wm * 64 + lm) * 72 + lq * 8;    // A frag base in Xs
  const int boff = (wn * 64 + lm) * 72 + lq * 8;    // B frag base in Ws
  const int hro  = (wm * 64 + lm) * 136 + lq * 8;   // A frag base in HL (phase 2)
  const int hwo  = (wm * 64 + lq * 4) * 136 + wn * 64 + lm;  // C->HL write base

  f32x4 acc2[4][4];
#pragma unroll
  for (int i = 0; i < 4; ++i)
#pragma unroll
    for (int j = 0; j < 4; ++j) acc2[i][j] = (f32x4){0.f, 0.f, 0.f, 0.f};

  for (int hc = 0; hc < 4; ++hc) {
    f32x4 acc1[4][4];
#pragma unroll
    for (int i = 0; i < 4; ++i)
#pragma unroll
      for (int j = 0; j < 4; ++j) acc1[i][j] = (f32x4){0.f, 0.f, 0.f, 0.f};

    // ---- phase 1: hidden chunk [128 m][128 h] = X * W1[:, hc*128:+128], K=512 ----
    for (int kk = 0; kk < 8; ++kk) {          // BK=64
      __syncthreads();                        // protect Xs/Ws from previous readers
#pragma unroll
      for (int p = 0; p < 4; ++p) {
        int row = sr + p * 32;
        *(bf16x8*)(Xs + row * 72 + sc) =
            *(const bf16x8*)(Xb + xbase + (size_t)row * 512 + kk * 64 + sc);
        *(bf16x8*)(Ws + row * 72 + sc) =
            *(const bf16x8*)(W1T + w1base + (size_t)(hc * 128 + row) * 512 + kk * 64 + sc);
      }
      __syncthreads();                        // staged data visible
#pragma unroll
      for (int u = 0; u < 2; ++u) {           // two k-steps of 32
        bf16x8 af[4], bfr[4];
#pragma unroll
        for (int t = 0; t < 4; ++t) af[t]  = *(const bf16x8*)(Xs + aoff + u * 32 + t * (16 * 72));
#pragma unroll
        for (int t = 0; t < 4; ++t) bfr[t] = *(const bf16x8*)(Ws + boff + u * 32 + t * (16 * 72));
#pragma unroll
        for (int i = 0; i < 4; ++i)
#pragma unroll
          for (int j = 0; j < 4; ++j)
            acc1[i][j] = __builtin_amdgcn_mfma_f32_16x16x32_bf16(af[i], bfr[j], acc1[i][j], 0, 0, 0);
      }
    }

    // ---- exact GELU, spill chunk to HL as bf16 [m][h] ----
#pragma unroll
    for (int i = 0; i < 4; ++i)
#pragma unroll
      for (int j = 0; j < 4; ++j)
#pragma unroll
        for (int r = 0; r < 4; ++r)
          HL[hwo + i * (16 * 136) + r * 136 + j * 16] = f2bf(gelu_exact(acc1[i][j][r]));

    // ---- phase 2: acc2 += gelu(chunk) * W2[hc*128:+128, :], K=128 ----
#pragma unroll
    for (int s = 0; s < 2; ++s) {             // BK=64
      __syncthreads();                        // phase-1 readers done; HL writes done
#pragma unroll
      for (int p = 0; p < 4; ++p) {
        int row = sr + p * 32;
        *(bf16x8*)(Ws + row * 72 + sc) =
            *(const bf16x8*)(W2T + w2base + (size_t)row * 512 + hc * 128 + s * 64 + sc);
      }
      __syncthreads();
#pragma unroll
      for (int u = 0; u < 2; ++u) {
        bf16x8 af[4], bfr[4];
#pragma unroll
        for (int t = 0; t < 4; ++t) af[t]  = *(const bf16x8*)(HL + hro + s * 64 + u * 32 + t * (16 * 136));
#pragma unroll
        for (int t = 0; t < 4; ++t) bfr[t] = *(const bf16x8*)(Ws + boff + u * 32 + t * (16 * 72));
#pragma unroll
        for (int i = 0; i < 4; ++i)
#pragma unroll
          for (int j = 0; j < 4; ++j)
            acc2[i][j] = __builtin_amdgcn_mfma_f32_16x16x32_bf16(af[i], bfr[j], acc2[i][j], 0, 0, 0);
      }
    }
  }

  // ---- epilogue: OUT[((tile*128+m)*128 + d4)*16 + e]  (fp32!) ----
  const int d4 = wn * 64 + lm;
  const size_t rowb = (size_t)tile * 128 + wm * 64 + lq * 4;
  const size_t base = (rowb * 128 + d4) * 16 + e;
#pragma unroll
  for (int i = 0; i < 4; ++i)
#pragma unroll
    for (int r = 0; r < 4; ++r)
#pragma unroll
      for (int j = 0; j < 4; ++j)
        OUT[base + (size_t)(i * 16 + r) * 2048 + j * 256] = acc2[i][j][r];
}

extern "C" void kernel_launch(void* const* d_in, const int* in_sizes, int n_in,
                              void* d_out, int out_size, void* d_ws, size_t ws_size,
                              hipStream_t stream)
{
  const void* x  = d_in[0];   // [4*2048][512]   fp32 (detector also handles bf16)
  const void* w1 = d_in[1];   // [16][512][512]
  const void* w2 = d_in[2];   // [16][512][128]
  float* out = (float*)d_out; // fp32 [8192][128][16]

  short* Xb  = (short*)d_ws;                  // 4,194,304 shorts (8.39 MB)
  short* w1t = Xb + 4194304;                  // [16][512][512]   (8.39 MB)
  short* w2t = w1t + 4194304;                 // [16][128][512]   (2.10 MB)
  int*  flag = (int*)(w2t + 1048576);

  detect_kernel<<<1, 64, 0, stream>>>((const unsigned short*)x, flag);
  prep_x<<<2048, 256, 0, stream>>>(x, Xb, flag);
  prep_w<<<dim3(8, 8, 16), 256, 0, stream>>>(w1, w1t, flag, 512, 512);
  prep_w<<<dim3(8, 2, 16), 256, 0, stream>>>(w2, w2t, flag, 512, 128);
  moe_kernel<<<dim3(1024), 256, 0, stream>>>(Xb, w1t, w2t, out);
}

// Round 6
// 235.045 us; speedup vs baseline: 1.5773x; 1.5773x over previous
//
#include <hip/hip_runtime.h>
#include <stdint.h>

typedef short bf16x8 __attribute__((ext_vector_type(8)));
typedef float f32x4 __attribute__((ext_vector_type(4)));

__device__ __forceinline__ void async_cp16(const void* g, short* lds) {
  __builtin_amdgcn_global_load_lds(
      (const __attribute__((address_space(1))) void*)g,
      (__attribute__((address_space(3))) void*)lds, 16, 0, 0);
}

// tanh-approx GELU via sigmoid; |err| < ~1e-3 abs, threshold is 4.3e-2.
__device__ __forceinline__ float gelu_f(float v) {
  float z = 1.5957691216057308f * (v + 0.044715f * v * v * v);
  return __fdividef(v, 1.0f + __expf(-z));
}

__device__ __forceinline__ short f2bf(float x) {  // RNE f32->bf16
  uint32_t u = __float_as_uint(x);
  u += 0x7fffu + ((u >> 16) & 1u);
  return (short)(u >> 16);
}

// ---------------------------------------------------------------------------
// One-launch prep: fp32 -> bf16 cast of X (contiguous) + per-expert
// transposes of W1 ([e][d][h] -> [e][h][d]) and W2 ([e][h][d4] -> [e][d4][h]).
//   blocks [0,2048):    X cast
//   blocks [2048,3072): W1 transpose (e = idx>>6, 8x8 tiles of 64)
//   blocks [3072,3328): W2 transpose (e = idx>>4, 8x2 tiles of 64)
// ---------------------------------------------------------------------------
__global__ __launch_bounds__(256)
void prep_all(const float* __restrict__ x, const float* __restrict__ w1,
              const float* __restrict__ w2, short* __restrict__ Xb,
              short* __restrict__ w1t, short* __restrict__ w2t)
{
  __shared__ __align__(16) short T[64][72];
  const int b = blockIdx.x;
  const int t = threadIdx.x;

  if (b < 2048) {                       // ---- X cast ----
    const int idx = (b * 256 + t) * 8;
    bf16x8 o;
#pragma unroll
    for (int u = 0; u < 8; ++u) o[u] = f2bf(x[idx + u]);
    *(bf16x8*)(Xb + idx) = o;
    return;
  }

  const float* src; short* dst; int e, r0, c0, R, C;
  if (b < 3072) {                       // ---- W1 ----
    int idx = b - 2048; e = idx >> 6; int rem = idx & 63;
    r0 = (rem >> 3) * 64; c0 = (rem & 7) * 64; R = 512; C = 512;
    src = w1; dst = w1t;
  } else {                              // ---- W2 ----
    int idx = b - 3072; e = idx >> 4; int rem = idx & 15;
    r0 = (rem >> 1) * 64; c0 = (rem & 1) * 64; R = 512; C = 128;
    src = w2; dst = w2t;
  }
  const float* s = src + (size_t)e * R * C;
  short* d       = dst + (size_t)e * R * C;
  const int i = t >> 3, j8 = t & 7;
#pragma unroll
  for (int p = 0; p < 2; ++p) {
    int ii = i + p * 32;
#pragma unroll
    for (int u = 0; u < 8; ++u)
      T[ii][j8 * 8 + u] = f2bf(s[(size_t)(r0 + ii) * C + c0 + j8 * 8 + u]);
  }
  __syncthreads();
#pragma unroll
  for (int p = 0; p < 2; ++p) {
    int ii = i + p * 32;
    bf16x8 v;
#pragma unroll
    for (int u = 0; u < 8; ++u) v[u] = T[j8 * 8 + u][ii];
    *(bf16x8*)(d + (size_t)(c0 + ii) * R + r0 + j8 * 8) = v;
  }
}

// ---------------------------------------------------------------------------
// Fused experts. One block = 128-token tile x 1 expert, 4 waves (2x2 of 64x64).
// Async global_load_lds (16B) staging, double-buffered K=32 slices, XOR quad
// swizzle. Xb: [8192][512] bf16. W1T: [16][512 h][512 d]. W2T: [16][128][512].
// staged==1: O = ws [16 e][8192 row][128 d4] fp32 (coalesced).
// staged==0: O = out [row][d4][16 e] fp32 (strided fallback).
// ---------------------------------------------------------------------------
__global__ __launch_bounds__(256, 2)
void moe_kernel(const short* __restrict__ Xb, const short* __restrict__ W1T,
                const short* __restrict__ W2T, float* __restrict__ O, int staged)
{
  __shared__ __align__(16) short SM[33792];        // 67.6 KB
  short* const Xs0 = SM;                           // [128][32]
  short* const Xs1 = SM + 4096;
  short* const Ws0 = SM + 8192;
  short* const Ws1 = SM + 12288;
  short* const HL  = SM + 16384;                   // [128][136]

  const int tid = threadIdx.x;
  const int l = tid & 63, w = tid >> 6;
  const int wm = w & 1, wn = w >> 1;
  const int e = blockIdx.x & 15;
  const int tile = blockIdx.x >> 4;

  // staging lane constants (lane -> base + lane*16B, packed [row][32 shorts])
  const int lrow = l >> 2, lq = l & 3;
  int ldso[2];
  const char *xg[2], *w1g[2], *w2g[2];
#pragma unroll
  for (int c = 0; c < 2; ++c) {
    int prow = w * 32 + c * 16 + lrow;                      // 0..127
    int qg = lq ^ ((prow >> 1) & 3);                        // XOR quad swizzle
    ldso[c] = (w * 32 + c * 16) * 32;
    xg[c]  = (const char*)Xb  + (size_t)(tile * 128 + prow) * 1024 + qg * 16;
    w1g[c] = (const char*)W1T + (size_t)e * 524288 + (size_t)prow * 1024 + qg * 16;
    w2g[c] = (const char*)W2T + (size_t)e * 131072 + (size_t)prow * 1024 + qg * 16;
  }

  // consumer lane constants (shorts); slot undoes the swizzle
  const int lm = l & 15;
  const int slot = (l >> 4) ^ ((lm >> 1) & 3);
  const int aoff = (wm * 64 + lm) * 32 + slot * 8;
  const int boff = (wn * 64 + lm) * 32 + slot * 8;
  const int hro  = (wm * 64 + lm) * 136 + (l >> 4) * 8;
  const int hwo  = (wm * 64 + (l >> 4) * 4) * 136 + wn * 64 + lm;

  f32x4 acc2[4][4];
#pragma unroll
  for (int i = 0; i < 4; ++i)
#pragma unroll
    for (int j = 0; j < 4; ++j) acc2[i][j] = (f32x4){0.f, 0.f, 0.f, 0.f};

  // prologue: stage hc=0, kk=0 into buf0
#pragma unroll
  for (int c = 0; c < 2; ++c) {
    async_cp16(xg[c],  Xs0 + ldso[c]);
    async_cp16(w1g[c], Ws0 + ldso[c]);
  }

  for (int hc = 0; hc < 4; ++hc) {
    f32x4 acc1[4][4];
#pragma unroll
    for (int i = 0; i < 4; ++i)
#pragma unroll
      for (int j = 0; j < 4; ++j) acc1[i][j] = (f32x4){0.f, 0.f, 0.f, 0.f};

    const size_t w1hc = (size_t)hc * 131072;   // 128 h-rows * 1024B

    // ---- phase 1: hidden[:, hc*128:+128] = X * W1, K=512 in 16 slices ----
#pragma unroll
    for (int kk = 0; kk < 16; ++kk) {
      __syncthreads();                         // drains vmcnt: current bufs ready
      if (kk < 15) {
        short* xb = ((kk + 1) & 1) ? Xs1 : Xs0;
        short* wb = ((kk + 1) & 1) ? Ws1 : Ws0;
#pragma unroll
        for (int c = 0; c < 2; ++c) {
          async_cp16(xg[c] + (kk + 1) * 64,         xb + ldso[c]);
          async_cp16(w1g[c] + w1hc + (kk + 1) * 64, wb + ldso[c]);
        }
      } else {                                 // prefetch phase-2 s=0 into Ws0
#pragma unroll
        for (int c = 0; c < 2; ++c)
          async_cp16(w2g[c] + hc * 256, Ws0 + ldso[c]);
      }
      const short* xb = (kk & 1) ? Xs1 : Xs0;
      const short* wb = (kk & 1) ? Ws1 : Ws0;
      bf16x8 af[4], bfr[4];
#pragma unroll
      for (int t = 0; t < 4; ++t) af[t]  = *(const bf16x8*)(xb + aoff + t * 512);
#pragma unroll
      for (int t = 0; t < 4; ++t) bfr[t] = *(const bf16x8*)(wb + boff + t * 512);
#pragma unroll
      for (int i = 0; i < 4; ++i)
#pragma unroll
        for (int j = 0; j < 4; ++j)
          acc1[i][j] = __builtin_amdgcn_mfma_f32_16x16x32_bf16(af[i], bfr[j], acc1[i][j], 0, 0, 0);
    }

    // ---- GELU + spill hidden chunk to LDS bf16 [m][h] ----
#pragma unroll
    for (int i = 0; i < 4; ++i)
#pragma unroll
      for (int j = 0; j < 4; ++j)
#pragma unroll
        for (int r = 0; r < 4; ++r)
          HL[hwo + i * 2176 + r * 136 + j * 16] = f2bf(gelu_f(acc1[i][j][r]));

    // ---- phase 2: acc2 += gelu(chunk) * W2 slice, K=128 in 4 slices ----
#pragma unroll
    for (int s = 0; s < 4; ++s) {
      __syncthreads();                         // HL writes + W2 slice staged
      if (s < 3) {
        short* wb = ((s + 1) & 1) ? Ws1 : Ws0;
#pragma unroll
        for (int c = 0; c < 2; ++c)
          async_cp16(w2g[c] + hc * 256 + (s + 1) * 64, wb + ldso[c]);
      } else if (hc < 3) {                     // prefetch next hc's kk=0
#pragma unroll
        for (int c = 0; c < 2; ++c) {
          async_cp16(xg[c],                              Xs0 + ldso[c]);
          async_cp16(w1g[c] + (size_t)(hc + 1) * 131072, Ws0 + ldso[c]);
        }
      }
      const short* wb = (s & 1) ? Ws1 : Ws0;
      bf16x8 af[4], bfr[4];
#pragma unroll
      for (int t = 0; t < 4; ++t) af[t]  = *(const bf16x8*)(HL + hro + t * 2176 + s * 32);
#pragma unroll
      for (int t = 0; t < 4; ++t) bfr[t] = *(const bf16x8*)(wb + boff + t * 512);
#pragma unroll
      for (int i = 0; i < 4; ++i)
#pragma unroll
        for (int j = 0; j < 4; ++j)
          acc2[i][j] = __builtin_amdgcn_mfma_f32_16x16x32_bf16(af[i], bfr[j], acc2[i][j], 0, 0, 0);
    }
  }

  // ---- epilogue ----
  const int d4 = wn * 64 + lm;
  const int lqr = (l >> 4) * 4;
  if (staged) {  // coalesced: OUTs[e][row][d4]
    const size_t base = ((size_t)e * 8192 + tile * 128 + wm * 64 + lqr) * 128 + d4;
#pragma unroll
    for (int i = 0; i < 4; ++i)
#pragma unroll
      for (int r = 0; r < 4; ++r)
#pragma unroll
        for (int j = 0; j < 4; ++j)
          O[base + (size_t)(i * 16 + r) * 128 + j * 16] = acc2[i][j][r];
  } else {       // direct strided fallback
    const size_t rowb = (size_t)tile * 128 + wm * 64 + lqr;
    const size_t base = (rowb * 128 + d4) * 16 + e;
#pragma unroll
    for (int i = 0; i < 4; ++i)
#pragma unroll
      for (int r = 0; r < 4; ++r)
#pragma unroll
        for (int j = 0; j < 4; ++j)
          O[base + (size_t)(i * 16 + r) * 2048 + j * 256] = acc2[i][j][r];
  }
}

// ---------------------------------------------------------------------------
// Permute: OUT[row][d4*16+e] = OUTs[e][row][d4]. Block = 8 rows.
// LDS T[8 r][16 e][132 d4] fp32 (pad 128->132).
// R4/R5 FATAL BUG FIXED HERE: second loop must be r=u>>9, c4=(u&511)*4
// (512 vec4 per 2048-float row). u>>8/(u&255) wrote rows 8..15 past the
// block's 8 rows -> OOB global writes (row up to 8207) -> HSA abort.
// ---------------------------------------------------------------------------
__global__ __launch_bounds__(256, 2)
void permute_kernel(const float* __restrict__ OUTs, float* __restrict__ OUT)
{
  __shared__ float T[8 * 16 * 132];     // 67.6 KB
  const int t = threadIdx.x;
  const int r0 = blockIdx.x * 8;
#pragma unroll
  for (int it = 0; it < 16; ++it) {
    int v = it * 256 + t;                       // vec4 id, [0,4096)
    int e = v >> 8, r = (v >> 5) & 7, q = v & 31;
    f32x4 d = *(const f32x4*)(OUTs + ((size_t)e * 8192 + r0 + r) * 128 + q * 4);
    *(f32x4*)(&T[(r * 16 + e) * 132 + q * 4]) = d;
  }
  __syncthreads();
#pragma unroll
  for (int it = 0; it < 16; ++it) {
    int u = it * 256 + t;                       // vec4 id, [0,4096)
    int r = u >> 9;                             // [0,8)   (was u>>8: OOB!)
    int c4 = (u & 511) * 4;                     // [0,2048) (was (u&255)*4)
    int d4 = c4 >> 4, e0 = c4 & 15;
    f32x4 o;
#pragma unroll
    for (int i = 0; i < 4; ++i) o[i] = T[(r * 16 + e0 + i) * 132 + d4];
    *(f32x4*)(OUT + (size_t)(r0 + r) * 2048 + c4) = o;
  }
}

extern "C" void kernel_launch(void* const* d_in, const int* in_sizes, int n_in,
                              void* d_out, int out_size, void* d_ws, size_t ws_size,
                              hipStream_t stream)
{
  const float* x  = (const float*)d_in[0];   // fp32 [8192][512]
  const float* w1 = (const float*)d_in[1];   // fp32 [16][512][512]
  const float* w2 = (const float*)d_in[2];   // fp32 [16][512][128]
  float* out = (float*)d_out;                // fp32 [8192][128][16]

  short* Xb  = (short*)d_ws;                 // 8.39 MB
  short* w1t = Xb + 4194304;                 // 8.39 MB
  short* w2t = w1t + 4194304;                // 2.10 MB
  float* OUTs = (float*)((char*)d_ws + 18874368);   // 67.1 MB
  const bool staged = ws_size >= 85983232ULL;

  prep_all<<<dim3(3328), 256, 0, stream>>>(x, w1, w2, Xb, w1t, w2t);
  moe_kernel<<<dim3(1024), 256, 0, stream>>>(Xb, w1t, w2t,
                                             staged ? OUTs : out, staged ? 1 : 0);
  if (staged)
    permute_kernel<<<dim3(1024), 256, 0, stream>>>(OUTs, out);
}